// Round 6
// baseline (97.561 us; speedup 1.0000x reference)
//
#include <hip/hip_runtime.h>

#define NROWS 2048
#define MLEN  3000
#define LPAD  4096
#define PAD0  548
#define NLVL  8
#define NT    512
#define RPB   2

union F4 { float4 v; float f[4]; };

// Light barrier: LDS-visibility only (s_waitcnt lgkmcnt(0) + s_barrier).
// Does NOT drain vmcnt, so details->global write-through stays in flight.
__device__ inline void lds_barrier() {
    asm volatile("s_waitcnt lgkmcnt(0)\n\ts_barrier" ::: "memory");
}
// Wave-local LDS visibility (same-wave producer/consumer, no s_barrier).
__device__ inline void wave_lds_fence() {
    asm volatile("s_waitcnt lgkmcnt(0)" ::: "memory");
}

// R6: s_setprio(1) around FMA bursts.  R7: filters in SGPRs.
// R8: lvl0 direct-from-global; final-approx repack folded into lvl7.
// R9: two rows per block (NT=512, 4 blocks/CU x 8 waves = 32 waves/CU).
// R10: BARRIER-FREE MIDDLE — analysis lvl3..7 + synthesis lvl7..3 all have
//      q<=64 work items, run entirely by wave 0 of each row with only
//      wave-local lgkmcnt fences (input approx2 is barriered after lvl2;
//      every middle producer/consumer is wave0 itself; d2/d1 mirrors in
//      sa[512..1024)/sb[1088..2112) are untouched by the middle).
//      vmcnt-drain barrier moved to the synth1->synth0 junction (protects
//      only the details0 global readback). Barrier phases: 16 -> 7.
__global__ __launch_bounds__(NT, 8) void despawn_kernel(
    const float* __restrict__ x,
    const float* __restrict__ scaling,
    const float* __restrict__ scaling_rec,
    float* __restrict__ recon_out,
    float* __restrict__ coef_out)
{
    // per row: SA 2048 | SB 2112 | CS 512  (4672 floats = 18688 B)
    __shared__ __align__(16) float LDSBUF[RPB][4672];

    const int tid = threadIdx.x;
    const int r   = tid >> 8;        // row slot within block
    const int t   = tid & 255;       // lane within row pipeline
    const int row = blockIdx.x * RPB + r;
    float* const sa = &LDSBUF[r][0];
    float* const sb = &LDSBUF[r][2048];
    float* const cs = &LDSBUF[r][4160];

    float* const crow = coef_out + (size_t)row * LPAD;
    const float* xr = x + (size_t)row * MLEN;

    // Desync co-resident blocks (consecutive ids round-robin across 8 XCDs).
    {
        const int lag = (blockIdx.x >> 3) & 3;
        for (int i = 0; i < lag; ++i) __builtin_amdgcn_s_sleep(8);
    }

    // ---------------- analysis level 0 : direct from global ----------------
    // out[j] = sum_k x_pad[(2j-k) mod 4096] f[k]; x_pad[i]=xr[clamp(i-548)],
    // i<0 wraps to hi pad (also clamps to xr[2999]).
    {
        float S[8], Wr[8];
#pragma unroll
        for (int k = 0; k < 8; ++k) { S[k] = scaling[k]; Wr[k] = scaling_rec[7 - k]; }
#pragma unroll
        for (int h = 0; h < 2; ++h) {
            const int j0 = 1024 * h;
            const int n0 = 2 * j0 + 8 * t - 8;
            F4 V0, V1, V2, V3;
            if (n0 >= PAD0 && n0 + 15 <= PAD0 + MLEN - 1) {
                const float4* src = reinterpret_cast<const float4*>(xr + (n0 - PAD0));
                V0.v = src[0]; V1.v = src[1]; V2.v = src[2]; V3.v = src[3];
            } else {
                const float x0  = xr[0];
                const float xhi = xr[MLEN - 1];
#pragma unroll
                for (int j = 0; j < 16; ++j) {
                    const int n = n0 + j;
                    const int m = (n < 0) ? n + LPAD : n;   // wrap region is all >= 3548
                    float val;
                    if (m < PAD0)              val = x0;
                    else if (m >= PAD0 + MLEN) val = xhi;
                    else                       val = xr[m - PAD0];
                    if (j < 4)       V0.f[j & 3] = val;
                    else if (j < 8)  V1.f[j & 3] = val;
                    else if (j < 12) V2.f[j & 3] = val;
                    else             V3.f[j & 3] = val;
                }
            }
            float e[8] = {V0.f[0],V0.f[2],V1.f[0],V1.f[2],V2.f[0],V2.f[2],V3.f[0],V3.f[2]};
            float o[8] = {V0.f[1],V0.f[3],V1.f[1],V1.f[3],V2.f[1],V2.f[3],V3.f[1],V3.f[3]};
            float ds[4], as[4];
            __builtin_amdgcn_s_setprio(1);
#pragma unroll
            for (int u = 0; u < 4; ++u) {
                float d = 0.f, a = 0.f;
#pragma unroll
                for (int m = 0; m < 4; ++m) {
                    const float vE = e[4 + u - m];
                    const float vO = o[3 + u - m];
                    d = fmaf(vE, Wr[2 * m], d);
                    d = fmaf(vO, -Wr[2 * m + 1], d);
                    a = fmaf(vE, S[2 * m], a);
                    a = fmaf(vO, S[2 * m + 1], a);
                }
                ds[u] = d; as[u] = a;
            }
            __builtin_amdgcn_s_setprio(0);
            F4 dv; dv.f[0] = ds[0]; dv.f[1] = ds[1]; dv.f[2] = ds[2]; dv.f[3] = ds[3];
            reinterpret_cast<float4*>(crow + j0)[t] = dv.v;      // details0 -> global
            *reinterpret_cast<float2*>(sa + (j0 >> 1) + 2 * t)        = make_float2(as[0], as[2]);
            *reinterpret_cast<float2*>(sa + 1024 + (j0 >> 1) + 2 * t) = make_float2(as[1], as[3]);
        }
    }
    lds_barrier();   // sa (approx0, split ev|od) complete

    // ------------- analysis levels 1..2 (barriered) + 3..7 (wave-local) -------------
    {
        float* cur = sa;
        float* alt = sb;
        int H = 1024;
        int coff = 2048;
        for (int lvl = 1; lvl <= 2; ++lvl) {
            float S[8], Wr[8];
#pragma unroll
            for (int k = 0; k < 8; ++k) {
                S[k]  = scaling[lvl * 8 + k];
                Wr[k] = scaling_rec[lvl * 8 + 7 - k];
            }
            const int q = H >> 2;          // 256, 128
            const int qm = q - 1;
            const float4* ev4 = reinterpret_cast<const float4*>(cur);
            const float4* od4 = reinterpret_cast<const float4*>(cur + H);
            float4* dst4 = reinterpret_cast<float4*>(crow + coff);
            float4* mir4 = (lvl == 1) ? reinterpret_cast<float4*>(sb + 1088)
                                      : reinterpret_cast<float4*>(sa + 512);
            if (t < q) {
                const int tt = t;
                F4 Ea, Eb, Oa, Ob;
                Ea.v = ev4[(tt - 1) & qm];
                Eb.v = ev4[tt];
                Oa.v = od4[(tt - 1) & qm];
                Ob.v = od4[tt];
                float e[8] = {Ea.f[0],Ea.f[1],Ea.f[2],Ea.f[3],Eb.f[0],Eb.f[1],Eb.f[2],Eb.f[3]};
                float o[8] = {Oa.f[0],Oa.f[1],Oa.f[2],Oa.f[3],Ob.f[0],Ob.f[1],Ob.f[2],Ob.f[3]};
                float ds[4], as[4];
                __builtin_amdgcn_s_setprio(1);
#pragma unroll
                for (int u = 0; u < 4; ++u) {
                    float d = 0.f, a = 0.f;
#pragma unroll
                    for (int m = 0; m < 4; ++m) {
                        const float vE = e[4 + u - m];
                        const float vO = o[3 + u - m];
                        d = fmaf(vE, Wr[2 * m], d);
                        d = fmaf(vO, -Wr[2 * m + 1], d);
                        a = fmaf(vE, S[2 * m], a);
                        a = fmaf(vO, S[2 * m + 1], a);
                    }
                    ds[u] = d; as[u] = a;
                }
                __builtin_amdgcn_s_setprio(0);
                F4 dv; dv.f[0] = ds[0]; dv.f[1] = ds[1]; dv.f[2] = ds[2]; dv.f[3] = ds[3];
                dst4[tt] = dv.v;     // details -> global, not drained
                mir4[tt] = dv.v;     // details -> LDS mirror
                *reinterpret_cast<float2*>(alt + 2 * tt)            = make_float2(as[0], as[2]);
                *reinterpret_cast<float2*>(alt + (H >> 1) + 2 * tt) = make_float2(as[1], as[3]);
            }
            lds_barrier();
            coff += H;
            float* tmp = cur; cur = alt; alt = tmp;
            H >>= 1;
        }
        // cur==sa (approx2 split in sa[0..512)), alt==sb, H==256, coff==3584

        // ---------------- barrier-free middle: wave 0 of each row ----------------
        if (t < 64) {
            // analysis lvl3..7
            for (int lvl = 3; lvl < NLVL; ++lvl) {
                float S[8], Wr[8];
#pragma unroll
                for (int k = 0; k < 8; ++k) {
                    S[k]  = scaling[lvl * 8 + k];
                    Wr[k] = scaling_rec[lvl * 8 + 7 - k];
                }
                const int q = H >> 2;      // 64,32,16,8,4
                const int qm = q - 1;
                const float4* ev4 = reinterpret_cast<const float4*>(cur);
                const float4* od4 = reinterpret_cast<const float4*>(cur + H);
                float4* dst4 = reinterpret_cast<float4*>(crow + coff);
                float4* mir4 = reinterpret_cast<float4*>(cs + (coff - 3584));
                if (t < q) {
                    const int tt = t;
                    F4 Ea, Eb, Oa, Ob;
                    Ea.v = ev4[(tt - 1) & qm];
                    Eb.v = ev4[tt];
                    Oa.v = od4[(tt - 1) & qm];
                    Ob.v = od4[tt];
                    float e[8] = {Ea.f[0],Ea.f[1],Ea.f[2],Ea.f[3],Eb.f[0],Eb.f[1],Eb.f[2],Eb.f[3]};
                    float o[8] = {Oa.f[0],Oa.f[1],Oa.f[2],Oa.f[3],Ob.f[0],Ob.f[1],Ob.f[2],Ob.f[3]};
                    float ds[4], as[4];
#pragma unroll
                    for (int u = 0; u < 4; ++u) {
                        float d = 0.f, a = 0.f;
#pragma unroll
                        for (int m = 0; m < 4; ++m) {
                            const float vE = e[4 + u - m];
                            const float vO = o[3 + u - m];
                            d = fmaf(vE, Wr[2 * m], d);
                            d = fmaf(vO, -Wr[2 * m + 1], d);
                            a = fmaf(vE, S[2 * m], a);
                            a = fmaf(vO, S[2 * m + 1], a);
                        }
                        ds[u] = d; as[u] = a;
                    }
                    F4 dv; dv.f[0] = ds[0]; dv.f[1] = ds[1]; dv.f[2] = ds[2]; dv.f[3] = ds[3];
                    dst4[tt] = dv.v;
                    mir4[tt] = dv.v;
                    if (lvl < NLVL - 1) {
                        *reinterpret_cast<float2*>(alt + 2 * tt)            = make_float2(as[0], as[2]);
                        *reinterpret_cast<float2*>(alt + (H >> 1) + 2 * tt) = make_float2(as[1], as[3]);
                    } else {
                        F4 av; av.f[0] = as[0]; av.f[1] = as[1]; av.f[2] = as[2]; av.f[3] = as[3];
                        *reinterpret_cast<float4*>(cs + 496 + 4 * tt)         = av.v;
                        *reinterpret_cast<float4*>(crow + LPAD - 16 + 4 * tt) = av.v;
                    }
                }
                wave_lds_fence();
                coff += H;
                float* tmp = cur; cur = alt; alt = tmp;
                H >>= 1;
            }

            // synthesis lvl7..3 (wave-local)
            const float* a = cs + 496;
            float* obuf = sa;          // 32->sa,64->sb,128->sa,256->sb,512->sa
            int len = 16;
            for (int lvl = NLVL - 1; lvl >= 3; --lvl) {
                float S[8], Wr[8];
#pragma unroll
                for (int k = 0; k < 8; ++k) {
                    S[k]  = scaling[lvl * 8 + k];
                    Wr[k] = scaling_rec[lvl * 8 + 7 - k];
                }
                const int Mout = len << 1;
                const int doff = LPAD - (LPAD >> lvl);
                const float4* d4 = reinterpret_cast<const float4*>(cs + (doff - 3584));
                const float4* a4 = reinterpret_cast<const float4*>(a);
                const int gq = Mout >> 3;      // 4,8,16,32,64
                const int fm = (len >> 2) - 1;
                if (t < gq) {
                    const int g = t;
                    F4 Da, Db, Aa, Ab;
                    Da.v = d4[g]; Db.v = d4[(g + 1) & fm];
                    Aa.v = a4[g]; Ab.v = a4[(g + 1) & fm];
                    float dd[8] = {Da.f[0],Da.f[1],Da.f[2],Da.f[3],Db.f[0],Db.f[1],Db.f[2],Db.f[3]};
                    float aa[8] = {Aa.f[0],Aa.f[1],Aa.f[2],Aa.f[3],Ab.f[0],Ab.f[1],Ab.f[2],Ab.f[3]};
                    float out[8];
#pragma unroll
                    for (int u = 0; u < 8; ++u) {
                        const int p = u & 1, c = (u + 1) >> 1;
                        float s = 0.f;
#pragma unroll
                        for (int m = 0; m < 4; ++m) {
                            const float w = Wr[p + 2 * m];
                            s = fmaf(dd[c + m], p ? -w : w, s);
                            s = fmaf(aa[c + m], S[p + 2 * m], s);
                        }
                        out[u] = s;
                    }
                    F4 o0, o1;
                    o0.f[0] = out[0]; o0.f[1] = out[1]; o0.f[2] = out[2]; o0.f[3] = out[3];
                    o1.f[0] = out[4]; o1.f[1] = out[5]; o1.f[2] = out[6]; o1.f[3] = out[7];
                    float4* ob4 = reinterpret_cast<float4*>(obuf + 8 * g);
                    ob4[0] = o0.v; ob4[1] = o1.v;
                }
                wave_lds_fence();
                a = obuf;
                obuf = (obuf == sa) ? sb : sa;
                len = Mout;
            }
            // exits with a==sa (512-approx), obuf==sb
        }
    }
    lds_barrier();   // publish wave0's sa[0..512) to waves 0-1 for synth2

    // ---------------- synthesis level 2 : gq=128 ----------------
    {
        float S[8], Wr[8];
#pragma unroll
        for (int k = 0; k < 8; ++k) {
            S[k]  = scaling[2 * 8 + k];
            Wr[k] = scaling_rec[2 * 8 + 7 - k];
        }
        const float4* d4 = reinterpret_cast<const float4*>(sa + 512);   // d2 mirror
        const float4* a4 = reinterpret_cast<const float4*>(sa);         // approx3-rec
        const int fm = 127;                                             // len=512
        if (t < 128) {
            const int g = t;
            F4 Da, Db, Aa, Ab;
            Da.v = d4[g]; Db.v = d4[(g + 1) & fm];
            Aa.v = a4[g]; Ab.v = a4[(g + 1) & fm];
            float dd[8] = {Da.f[0],Da.f[1],Da.f[2],Da.f[3],Db.f[0],Db.f[1],Db.f[2],Db.f[3]};
            float aa[8] = {Aa.f[0],Aa.f[1],Aa.f[2],Aa.f[3],Ab.f[0],Ab.f[1],Ab.f[2],Ab.f[3]};
            float out[8];
            __builtin_amdgcn_s_setprio(1);
#pragma unroll
            for (int u = 0; u < 8; ++u) {
                const int p = u & 1, c = (u + 1) >> 1;
                float s = 0.f;
#pragma unroll
                for (int m = 0; m < 4; ++m) {
                    const float w = Wr[p + 2 * m];
                    s = fmaf(dd[c + m], p ? -w : w, s);
                    s = fmaf(aa[c + m], S[p + 2 * m], s);
                }
                out[u] = s;
            }
            __builtin_amdgcn_s_setprio(0);
            F4 o0, o1;
            o0.f[0] = out[0]; o0.f[1] = out[1]; o0.f[2] = out[2]; o0.f[3] = out[3];
            o1.f[0] = out[4]; o1.f[1] = out[5]; o1.f[2] = out[6]; o1.f[3] = out[7];
            float4* ob4 = reinterpret_cast<float4*>(sb + 8 * g);
            ob4[0] = o0.v; ob4[1] = o1.v;
        }
    }
    lds_barrier();

    // ---------------- synthesis level 1 : gq=256 ----------------
    {
        float S[8], Wr[8];
#pragma unroll
        for (int k = 0; k < 8; ++k) {
            S[k]  = scaling[1 * 8 + k];
            Wr[k] = scaling_rec[1 * 8 + 7 - k];
        }
        const float4* d4 = reinterpret_cast<const float4*>(sb + 1088);  // d1 mirror
        const float4* a4 = reinterpret_cast<const float4*>(sb);         // approx2-rec
        const int fm = 255;                                             // len=1024
        {
            const int g = t;
            F4 Da, Db, Aa, Ab;
            Da.v = d4[g]; Db.v = d4[(g + 1) & fm];
            Aa.v = a4[g]; Ab.v = a4[(g + 1) & fm];
            float dd[8] = {Da.f[0],Da.f[1],Da.f[2],Da.f[3],Db.f[0],Db.f[1],Db.f[2],Db.f[3]};
            float aa[8] = {Aa.f[0],Aa.f[1],Aa.f[2],Aa.f[3],Ab.f[0],Ab.f[1],Ab.f[2],Ab.f[3]};
            float out[8];
            __builtin_amdgcn_s_setprio(1);
#pragma unroll
            for (int u = 0; u < 8; ++u) {
                const int p = u & 1, c = (u + 1) >> 1;
                float s = 0.f;
#pragma unroll
                for (int m = 0; m < 4; ++m) {
                    const float w = Wr[p + 2 * m];
                    s = fmaf(dd[c + m], p ? -w : w, s);
                    s = fmaf(aa[c + m], S[p + 2 * m], s);
                }
                out[u] = s;
            }
            __builtin_amdgcn_s_setprio(0);
            F4 o0, o1;
            o0.f[0] = out[0]; o0.f[1] = out[1]; o0.f[2] = out[2]; o0.f[3] = out[3];
            o1.f[0] = out[4]; o1.f[1] = out[5]; o1.f[2] = out[6]; o1.f[3] = out[7];
            float4* ob4 = reinterpret_cast<float4*>(sa + 8 * g);
            ob4[0] = o0.v; ob4[1] = o1.v;
        }
    }
    // FULL drain: every wave's crow stores (incl. details0 from lvl0) must be
    // visible before synth0's global readback of details0.
    asm volatile("s_waitcnt vmcnt(0) lgkmcnt(0)\n\ts_barrier" ::: "memory");

    // ---------------- synthesis level 0 : straight to recon ----------------
    {
        float S[8], Wr[8];
#pragma unroll
        for (int k = 0; k < 8; ++k) { S[k] = scaling[k]; Wr[k] = scaling_rec[7 - k]; }
        const float4* d4 = reinterpret_cast<const float4*>(crow);   // details0 (L2-warm)
        const float4* a4 = reinterpret_cast<const float4*>(sa);     // 2048 approx
        const int fm = 511;
        float* const ro = recon_out + (size_t)row * MLEN;
        for (int g = t; g < (LPAD >> 3); g += 256) {
            F4 Da, Db, Aa, Ab;
            Da.v = d4[g]; Db.v = d4[(g + 1) & fm];
            Aa.v = a4[g]; Ab.v = a4[(g + 1) & fm];
            float dd[8] = {Da.f[0],Da.f[1],Da.f[2],Da.f[3],Db.f[0],Db.f[1],Db.f[2],Db.f[3]};
            float aa[8] = {Aa.f[0],Aa.f[1],Aa.f[2],Aa.f[3],Ab.f[0],Ab.f[1],Ab.f[2],Ab.f[3]};
            float out[8];
            __builtin_amdgcn_s_setprio(1);
#pragma unroll
            for (int u = 0; u < 8; ++u) {
                const int p = u & 1, c = (u + 1) >> 1;
                float s = 0.f;
#pragma unroll
                for (int m = 0; m < 4; ++m) {
                    const float w = Wr[p + 2 * m];
                    s = fmaf(dd[c + m], p ? -w : w, s);
                    s = fmaf(aa[c + m], S[p + 2 * m], s);
                }
                out[u] = s;
            }
            __builtin_amdgcn_s_setprio(0);
            const int n0 = 8 * g;
            if (n0 >= PAD0 && n0 + 8 <= PAD0 + MLEN) {
                F4 o0, o1;
                o0.f[0] = out[0]; o0.f[1] = out[1]; o0.f[2] = out[2]; o0.f[3] = out[3];
                o1.f[0] = out[4]; o1.f[1] = out[5]; o1.f[2] = out[6]; o1.f[3] = out[7];
                float4* r4 = reinterpret_cast<float4*>(ro + (n0 - PAD0));
                r4[0] = o0.v; r4[1] = o1.v;
            } else {
#pragma unroll
                for (int u = 0; u < 8; ++u) {
                    const int n = n0 + u;
                    if (n >= PAD0 && n < PAD0 + MLEN) ro[n - PAD0] = out[u];
                }
            }
        }
    }
}

extern "C" void kernel_launch(void* const* d_in, const int* in_sizes, int n_in,
                              void* d_out, int out_size, void* d_ws, size_t ws_size,
                              hipStream_t stream) {
    const float* x           = (const float*)d_in[0];
    const float* scaling     = (const float*)d_in[1];
    const float* scaling_rec = (const float*)d_in[2];
    float* recon = (float*)d_out;                       // 2048*3000 floats
    float* coefo = recon + (size_t)NROWS * MLEN;        // 2048*4096 floats
    despawn_kernel<<<dim3(NROWS / RPB), dim3(NT), 0, stream>>>(x, scaling, scaling_rec,
                                                               recon, coefo);
    (void)in_sizes; (void)n_in; (void)out_size; (void)d_ws; (void)ws_size;
}